// Round 7
// baseline (33.133 us; speedup 1.0000x reference)
//
#include <hip/hip_runtime.h>
#include <hip/hip_bf16.h>

// FilterbankLinear: out[b, j*8+o] = sum_{c,t} x[b,c,s_j+t] * w[j*8+o, c*32+t]
// s_j = j (j<4063), s_4063 = 4064.
// Block = 8 windows, 8 waves (512 thr), one window/wave, grid 508 (2 blk/CU).
// GROUPED K: 4 channels per barrier step (21 = 5*4+1) so each w row is read
// as 512B contiguous bursts (DRAM row-activation amortization) instead of
// 128B @ stride 2688. x: fp32 LDS stage via global_load_lds dwordx4, 4-ch
// buffers, double-buffered, counted vmcnt + raw s_barrier. w: 8-float4
// register double-buffer (static-indexed names). Consume path = R5 (proven).

#define NF 4096
#define NC 21
#define WIN 32
#define OC 8
#define NWIN 4064
#define NKTOT (OC * NWIN)
#define DD (NC * WIN)       // 672
#define JB 8
#define NBLK (NWIN / JB)    // 508
#define XROWB 272           // 17 chunks * 16B per x row in LDS
#define XBUFB 9216          // per-channel buffer (576 chunks * 16B)
#define GBUF (4 * XBUFB)    // 4-channel group buffer = 36864 B

typedef short short8 __attribute__((ext_vector_type(8)));
typedef float f32x4 __attribute__((ext_vector_type(4)));

static __device__ __forceinline__ short f2bf(float f) {
  __bf16 h = (__bf16)f;
  return __builtin_bit_cast(short, h);
}
static __device__ __forceinline__ short8 pk8w(float4 a, float4 b) {
  short8 v;
  v[0]=f2bf(a.x); v[1]=f2bf(a.y); v[2]=f2bf(a.z); v[3]=f2bf(a.w);
  v[4]=f2bf(b.x); v[5]=f2bf(b.y); v[6]=f2bf(b.z); v[7]=f2bf(b.w);
  return v;
}
static __device__ __forceinline__ short8 pk8(float a, float b, float c, float d,
                                             float e, float f, float g, float h) {
  short8 v;
  v[0]=f2bf(a); v[1]=f2bf(b); v[2]=f2bf(c); v[3]=f2bf(d);
  v[4]=f2bf(e); v[5]=f2bf(f); v[6]=f2bf(g); v[7]=f2bf(h);
  return v;
}
// select 8 consecutive floats out of 12 by wave-uniform u (static indices)
static __device__ __forceinline__ short8 sel8(f32x4 a, f32x4 b, f32x4 c, int u) {
  switch (u & 3) {
    case 0:  return pk8(a[0],a[1],a[2],a[3],b[0],b[1],b[2],b[3]);
    case 1:  return pk8(a[1],a[2],a[3],b[0],b[1],b[2],b[3],c[0]);
    case 2:  return pk8(a[2],a[3],b[0],b[1],b[2],b[3],c[0],c[1]);
    default: return pk8(a[3],b[0],b[1],b[2],b[3],c[0],c[1],c[2]);
  }
}

__global__ __launch_bounds__(512, 4) void fb_v7(const float* __restrict__ x,
                                                const float* __restrict__ w,
                                                float* __restrict__ out) {
  __shared__ __align__(16) char xlds[2 * GBUF];   // 73728 B
  const int lane = threadIdx.x & 63;
  const int wv   = threadIdx.x >> 6;

  // bijective XCD swizzle (nwg=508: q=63, r=4)
  const int orig = blockIdx.x;
  const int xcd = orig & 7, sidx = orig >> 3;
  const int blk = (xcd < 4 ? xcd * 64 : 256 + (xcd - 4) * 63) + sidx;
  const int j0 = blk * JB;
  const int a0 = (j0 < NF - 68) ? j0 : (NF - 68);

  const int n  = lane & 15;
  const int o  = n & 7;
  const int kq = lane >> 4;

  const int jg = j0 + wv;
  const int sv = (jg == NWIN - 1) ? (NF - WIN) : jg;
  const int rj = sv - a0;
  const int u  = rj & 3;
  const int Cw = rj >> 2;
  const int off0 = n * XROWB + (Cw + 2 * kq) * 16;
  const int off1 = (16 + n) * XROWB + (Cw + 2 * kq) * 16;

  // ---- staging op precompute: GS=4 groups have 36 ops; wave wv takes
  // q = wv + 8k, k=0..4 (k=4 only when wv<4). op q -> (ch q/9, chunk q%9).
  int xo[5], lo[5];
  #pragma unroll
  for (int k = 0; k < 5; ++k) {
    const int q = wv + 8 * k;
    const int cg = q / 9, ck = q - cg * 9;
    int id = ck * 64 + lane; if (id > 543) id = 543;   // dup into row pad
    const int bb = id / 17, pp = id - bb * 17;
    xo[k] = (bb * NC + cg) * NF + a0 + pp * 4;
    lo[k] = cg * XBUFB + bb * XROWB + pp * 16;
  }
  // tail group (ch 20, 9 ops): wave wv -> chunk wv; wave 0 also chunk 8
  const int id5 = wv * 64 + lane;
  const int b5 = id5 / 17, p5 = id5 - b5 * 17;
  const int xo5 = (b5 * NC + 20) * NF + a0 + p5 * 4;
  const int lo5 = b5 * XROWB + p5 * 16;
  int id5b = 512 + lane; if (id5b > 543) id5b = 543;
  const int b5b = id5b / 17, p5b = id5b - b5b * 17;
  const int xo5b = (b5b * NC + 20) * NF + a0 + p5b * 4;
  const int lo5b = b5b * XROWB + p5b * 16;

  const float* wp = w + ((size_t)jg * OC + o) * DD + kq * 8;

  f32x4 acc0 = {0,0,0,0}, acc1 = {0,0,0,0};

#define GLL(GOFF, LOFF) \
  __builtin_amdgcn_global_load_lds( \
    (const __attribute__((address_space(1))) unsigned int*)(x + (GOFF)), \
    (__attribute__((address_space(3))) unsigned int*)(xlds + (LOFF)), 16, 0, 0)

#define STAGE_G(GG) { \
    const int cb_ = ((GG) & 1) * GBUF, gb_ = (GG) * 4 * NF; \
    GLL(xo[0] + gb_, cb_ + lo[0]); \
    GLL(xo[1] + gb_, cb_ + lo[1]); \
    GLL(xo[2] + gb_, cb_ + lo[2]); \
    GLL(xo[3] + gb_, cb_ + lo[3]); \
    if (wv < 4) GLL(xo[4] + gb_, cb_ + lo[4]); }

#define STAGE_TAIL() { \
    GLL(xo5, GBUF + lo5); \
    if (wv == 0) GLL(xo5b, GBUF + lo5b); }

#define LOADW(G, P) { \
    const float* p_ = wp + (size_t)(G) * 4 * WIN; \
    P##0a = *(const float4*)(p_);      P##0b = *(const float4*)(p_ + 4); \
    P##1a = *(const float4*)(p_ + 32); P##1b = *(const float4*)(p_ + 36); \
    P##2a = *(const float4*)(p_ + 64); P##2b = *(const float4*)(p_ + 68); \
    P##3a = *(const float4*)(p_ + 96); P##3b = *(const float4*)(p_ + 100); }

#define COMPUTE_CH(XB, WA, WB) { \
    short8 fbw_ = pk8w(WA, WB); \
    f32x4 ra_ = *(const f32x4*)((XB) + off0); \
    f32x4 rb_ = *(const f32x4*)((XB) + off0 + 16); \
    f32x4 rc_ = *(const f32x4*)((XB) + off0 + 32); \
    acc0 = __builtin_amdgcn_mfma_f32_16x16x32_bf16(sel8(ra_,rb_,rc_,u), fbw_, acc0, 0,0,0); \
    ra_ = *(const f32x4*)((XB) + off1); \
    rb_ = *(const f32x4*)((XB) + off1 + 16); \
    rc_ = *(const f32x4*)((XB) + off1 + 32); \
    acc1 = __builtin_amdgcn_mfma_f32_16x16x32_bf16(sel8(ra_,rb_,rc_,u), fbw_, acc1, 0,0,0); }

  float4 c0a, c0b, c1a, c1b, c2a, c2b, c3a, c3b;
  float4 n0a, n0b, n1a, n1b, n2a, n2b, n3a, n3b;

  // ---- prologue: stage group 0 -> buf0; w(group 0) -> regs ----
  STAGE_G(0);
  LOADW(0, c);

#define BODY4(G) { \
    asm volatile("s_waitcnt vmcnt(8)" ::: "memory"); \
    __builtin_amdgcn_s_barrier(); \
    __builtin_amdgcn_sched_barrier(0); \
    if ((G) < 4) { STAGE_G((G) + 1); LOADW((G) + 1, n); } \
    else { \
      STAGE_TAIL(); \
      const float* p_ = wp + 20 * WIN; \
      n0a = *(const float4*)(p_); n0b = *(const float4*)(p_ + 4); \
    } \
    __builtin_amdgcn_sched_barrier(0); \
    const char* xb_ = xlds + ((G) & 1) * GBUF; \
    COMPUTE_CH(xb_,             c0a, c0b); \
    COMPUTE_CH(xb_ + XBUFB,     c1a, c1b); \
    COMPUTE_CH(xb_ + 2*XBUFB,   c2a, c2b); \
    COMPUTE_CH(xb_ + 3*XBUFB,   c3a, c3b); \
    c0a = n0a; c0b = n0b; c1a = n1a; c1b = n1b; \
    c2a = n2a; c2b = n2b; c3a = n3a; c3b = n3b; }

  BODY4(0); BODY4(1); BODY4(2); BODY4(3); BODY4(4);

  // ---- tail body: channel 20 (group 5, buf1, ch-slot 0) ----
  asm volatile("s_waitcnt vmcnt(2)" ::: "memory");
  __builtin_amdgcn_s_barrier();
  __builtin_amdgcn_sched_barrier(0);
  COMPUTE_CH(xlds + GBUF, c0a, c0b);

#undef BODY4
#undef COMPUTE_CH
#undef LOADW
#undef STAGE_TAIL
#undef STAGE_G
#undef GLL

  if (n < 8) {
    const int m0 = kq * 4;
    #pragma unroll
    for (int e = 0; e < 4; ++e) {
      out[(size_t)(m0 + e)      * NKTOT + (size_t)jg * OC + n] = acc0[e];
      out[(size_t)(m0 + e + 16) * NKTOT + (size_t)jg * OC + n] = acc1[e];
    }
  }
}

extern "C" void kernel_launch(void* const* d_in, const int* in_sizes, int n_in,
                              void* d_out, int out_size, void* d_ws, size_t ws_size,
                              hipStream_t stream) {
  const float* x = (const float*)d_in[0];
  const float* w = (const float*)d_in[1];
  float* out = (float*)d_out;
  dim3 grid(NBLK), block(512);
  hipLaunchKernelGGL(fb_v7, grid, block, 0, stream, x, w, out);
}